// Round 13
// baseline (179.394 us; speedup 1.0000x reference)
//
#include <hip/hip_runtime.h>
#include <hip/hip_bf16.h>
#include <hip/hip_fp16.h>

#define CS 768
#define NTOK 1024
#define CZ 128
#define NH 12
#define HD 64
#define JC 16             // j-chunks of 64
#define ROWW 72           // f16 per score row in LDS (64 + 8 pad)
#define ZHS 1160          // f16 per head plane (16*72 + 8 pad)

typedef __attribute__((ext_vector_type(8))) short bf16x8;
typedef __attribute__((ext_vector_type(4))) float f32x4;
typedef __attribute__((ext_vector_type(8))) unsigned short ushort8_t;
typedef __attribute__((ext_vector_type(4))) unsigned short ushort4_t;

__device__ inline unsigned short f2bf(float f) {
  __hip_bfloat16 h = __float2bfloat16(f);
  return *reinterpret_cast<unsigned short*>(&h);
}
__device__ inline float bf2f(unsigned short u) {
  union { unsigned int i; float f; } c; c.i = ((unsigned int)u) << 16;
  return c.f;
}
__device__ inline unsigned int cvtpk_bf16(float lo, float hi) {
  unsigned int r;
  asm("v_cvt_pk_bf16_f32 %0, %1, %2" : "=v"(r) : "v"(lo), "v"(hi));
  return r;
}
__device__ inline unsigned int cvtpk_f16(float lo, float hi) {
  unsigned int r;
  asm("v_cvt_pkrtz_f16_f32 %0, %1, %2" : "=v"(r) : "v"(lo), "v"(hi));
  return r;
}

// ---------------- prep: LN(s)->bf16  +  transpose/convert 5 weights ----------------
__global__ __launch_bounds__(256) void prep_kernel(const float* __restrict__ s,
    const float* __restrict__ sc, const float* __restrict__ bi, unsigned short* __restrict__ sn,
    const float* __restrict__ W0, const float* __restrict__ W1, const float* __restrict__ W2,
    const float* __restrict__ W3, const float* __restrict__ W4, unsigned short* __restrict__ wt) {
  __shared__ float tile[64][65];
  int tid = threadIdx.x;
  if (blockIdx.x < NTOK) {
    int row = blockIdx.x;
    const float* x = s + (size_t)row * CS;
    float v0 = x[tid], v1 = x[tid + 256], v2 = x[tid + 512];
    float sum = v0 + v1 + v2;
    float sq  = v0*v0 + v1*v1 + v2*v2;
    for (int off = 1; off < 64; off <<= 1) {
      sum += __shfl_xor(sum, off);
      sq  += __shfl_xor(sq,  off);
    }
    __shared__ float ws1[4], ws2[4];
    if ((tid & 63) == 0) { ws1[tid >> 6] = sum; ws2[tid >> 6] = sq; }
    __syncthreads();
    float S = ws1[0] + ws1[1] + ws1[2] + ws1[3];
    float Q = ws2[0] + ws2[1] + ws2[2] + ws2[3];
    float mu  = S * (1.f / CS);
    float var = Q * (1.f / CS) - mu * mu;
    float rs  = rsqrtf(var + 1e-5f);
    unsigned short* y = sn + (size_t)row * CS;
    y[tid]       = f2bf((v0 - mu) * rs * sc[tid]       + bi[tid]);
    y[tid + 256] = f2bf((v1 - mu) * rs * sc[tid + 256] + bi[tid + 256]);
    y[tid + 512] = f2bf((v2 - mu) * rs * sc[tid + 512] + bi[tid + 512]);
  } else {
    int bz = blockIdx.x - NTOK;           // [0, 720)
    int w = bz / 144, rem = bz % 144;
    int kt = rem % 12, nt = rem / 12;
    const float* W = w == 0 ? W0 : w == 1 ? W1 : w == 2 ? W2 : w == 3 ? W3 : W4;
    unsigned short* Wt = wt + (size_t)w * CS * CS;
    int k0 = kt * 64, n0 = nt * 64;
    #pragma unroll
    for (int it = 0; it < 4; ++it) {
      int r = (tid >> 4) + it * 16;
      int c = (tid & 15) * 4;
      float4 vv = *(const float4*)(W + (size_t)(k0 + r) * CS + n0 + c);
      tile[r][c] = vv.x; tile[r][c+1] = vv.y; tile[r][c+2] = vv.z; tile[r][c+3] = vv.w;
    }
    __syncthreads();
    #pragma unroll
    for (int it = 0; it < 2; ++it) {
      int idx = tid + it * 256;
      int n = idx >> 3, k8 = (idx & 7) * 8;
      ushort8_t o;
      #pragma unroll
      for (int e = 0; e < 8; ++e) o[e] = f2bf(tile[k8 + e][n]);
      *(ushort8_t*)(Wt + (size_t)(n0 + n) * CS + k0 + k8) = o;
    }
  }
}

// ---------------- qkvg GEMM (standalone): [1024x768] @ [768x3072 sections] ----------------
__global__ __launch_bounds__(256) void qkvg_gemm(const unsigned short* __restrict__ A,
    const unsigned short* __restrict__ Wt, const float* __restrict__ bq,
    unsigned short* __restrict__ qb, unsigned short* __restrict__ kb,
    unsigned short* __restrict__ vtb, unsigned short* __restrict__ gbuf) {
  __shared__ __align__(16) unsigned short As[64][40];
  __shared__ __align__(16) unsigned short Bs[64][40];
  int tid = threadIdx.x;
  int wid = tid >> 6, lane = tid & 63;
  int lrow = lane & 15, lk8 = (lane >> 4) * 8;
  int row0 = blockIdx.y * 64, col0 = blockIdx.x * 64;   // col0 in [0,3072)
  int ar = tid >> 2, ak = (tid & 3) * 8;
  f32x4 acc[4] = {};
  for (int k0 = 0; k0 < CS; k0 += 32) {
    *(ushort8_t*)&As[ar][ak] = *(const ushort8_t*)(A  + (size_t)(row0 + ar) * CS + k0 + ak);
    *(ushort8_t*)&Bs[ar][ak] = *(const ushort8_t*)(Wt + (size_t)(col0 + ar) * CS + k0 + ak);
    __syncthreads();
    bf16x8 af = *(bf16x8*)&As[wid * 16 + lrow][lk8];
    #pragma unroll
    for (int nb = 0; nb < 4; ++nb) {
      bf16x8 bfr = *(bf16x8*)&Bs[nb * 16 + lrow][lk8];
      acc[nb] = __builtin_amdgcn_mfma_f32_16x16x32_bf16(af, bfr, acc[nb], 0, 0, 0);
    }
    __syncthreads();
  }
  int sect = col0 / CS;          // 0=q 1=k 2=v 3=g
  int ncol0 = col0 - sect * CS;
  int grow0 = row0 + wid * 16 + (lane >> 4) * 4;
  if (sect == 2) {
    // V transposed + column-permuted to PV's B-fragment k-slot order
    int jperm0 = ((grow0 >> 5) << 5) + 8 * (lane >> 4) + 4 * (wid & 1);
    #pragma unroll
    for (int nb = 0; nb < 4; ++nb) {
      int dg = ncol0 + nb * 16 + lrow;
      ushort4_t o;
      #pragma unroll
      for (int r = 0; r < 4; ++r) o[r] = f2bf(acc[nb][r]);
      *(ushort4_t*)(vtb + (size_t)dg * NTOK + jperm0) = o;
    }
  } else {
    unsigned short* dst = sect == 0 ? qb : sect == 1 ? kb : gbuf;
    #pragma unroll
    for (int nb = 0; nb < 4; ++nb) {
      int gcol = ncol0 + nb * 16 + lrow;
      float bv = (sect == 0) ? bq[gcol] : 0.f;
      #pragma unroll
      for (int r = 0; r < 4; ++r) {
        float val = acc[nb][r] + bv;
        if (sect == 3) val = 1.f / (1.f + __expf(-val));
        dst[(size_t)(grow0 + r) * CS + gcol] = f2bf(val);
      }
    }
  }
}

// ---------------- fused zb + flash: block = (16 i-rows, 64 j-cols, 12 heads) ----------------
__global__ __launch_bounds__(256) void zbflash_kernel(const float* __restrict__ z,
    const float* __restrict__ gs, const float* __restrict__ gb,
    const float* __restrict__ Wz, const float* __restrict__ mask,
    const unsigned short* __restrict__ qb, const unsigned short* __restrict__ kb,
    const unsigned short* __restrict__ vtb,
    float* __restrict__ Opart, float* __restrict__ lsum) {
  __shared__ __half zs[NH * ZHS];            // 12 * 1160 * 2B = 27.8 KB
  const int i0 = blockIdx.x * 16;
  const int jc = blockIdx.y;
  const int j0 = jc * 64;
  const int tid = threadIdx.x;
  const int w = tid >> 6, lane = tid & 63;
  const int il = lane & 15, qg = lane >> 4;
  const float QKS = 0.125f * 1.44269504f;

  // --- W' = sc*Wz split-bf16 fragments + bias-dot ---
  bf16x8 whi[4], wlo[4];
  float bh = 0.f;
  #pragma unroll
  for (int m = 0; m < 4; ++m) {
    union { unsigned short u[8]; bf16x8 v; } hi, lo;
    #pragma unroll
    for (int e = 0; e < 8; ++e) {
      int c = 32 * m + 8 * qg + e;
      float wv = (il < NH) ? Wz[c * NH + il] : 0.f;
      bh = fmaf(gb[c], wv, bh);
      float wp = gs[c] * wv;
      unsigned short h = f2bf(wp);
      hi.u[e] = h;
      lo.u[e] = f2bf(wp - bf2f(h));
    }
    whi[m] = hi.v; wlo[m] = lo.v;
  }
  bh += __shfl_xor(bh, 16);
  bh += __shfl_xor(bh, 32);

  // --- Phase 1: zb tile. 64 groups of 16 pairs; wave w does 16 ---
  for (int it = 0; it < 16; ++it) {
    int group = w * 16 + it;
    int i_local = group >> 2;               // 0..15
    int jseg = group & 3;                   // 0..3 (16-col segments)
    const float* zrow = z + ((size_t)(i0 + i_local) * NTOK + j0 + jseg * 16 + il) * CZ;
    float zv[32];
    #pragma unroll
    for (int m = 0; m < 4; ++m) {
      float4 a = *(const float4*)(zrow + 32 * m + 8 * qg);
      float4 b = *(const float4*)(zrow + 32 * m + 8 * qg + 4);
      zv[m*8+0] = a.x; zv[m*8+1] = a.y; zv[m*8+2] = a.z; zv[m*8+3] = a.w;
      zv[m*8+4] = b.x; zv[m*8+5] = b.y; zv[m*8+6] = b.z; zv[m*8+7] = b.w;
    }
    float sum = 0.f, sq = 0.f;
    #pragma unroll
    for (int e = 0; e < 32; ++e) { sum += zv[e]; sq = fmaf(zv[e], zv[e], sq); }
    sum += __shfl_xor(sum, 16); sum += __shfl_xor(sum, 32);
    sq  += __shfl_xor(sq,  16); sq  += __shfl_xor(sq,  32);
    float mu  = sum * (1.f / CZ);
    float var = sq * (1.f / CZ) - mu * mu;
    float rs  = rsqrtf(var + 1e-5f);
    float nmr = -mu * rs;
    f32x4 acc = {};
    #pragma unroll
    for (int m = 0; m < 4; ++m) {
      union { unsigned int u[4]; bf16x8 v; } hi;
      #pragma unroll
      for (int e2 = 0; e2 < 4; ++e2) {
        float n0 = fmaf(zv[m*8+e2*2],     rs, nmr);
        float n1 = fmaf(zv[m*8+e2*2 + 1], rs, nmr);
        hi.u[e2] = cvtpk_bf16(n0, n1);
      }
      acc = __builtin_amdgcn_mfma_f32_16x16x32_bf16(hi.v, whi[m], acc, 0, 0, 0);
      acc = __builtin_amdgcn_mfma_f32_16x16x32_bf16(hi.v, wlo[m], acc, 0, 0, 0);
    }
    if (il < NH) {
      int jl = jseg * 16 + 4 * qg;          // 0..63, multiple of 4
      float4 mk = *(const float4*)(mask + j0 + jl);
      float o0 = (acc[0] + bh + (1.f - mk.x) * -1000000.0f) * 1.44269504f - 16.f;
      float o1 = (acc[1] + bh + (1.f - mk.y) * -1000000.0f) * 1.44269504f - 16.f;
      float o2 = (acc[2] + bh + (1.f - mk.z) * -1000000.0f) * 1.44269504f - 16.f;
      float o3 = (acc[3] + bh + (1.f - mk.w) * -1000000.0f) * 1.44269504f - 16.f;
      unsigned int p01 = cvtpk_f16(o0, o1);
      unsigned int p23 = cvtpk_f16(o2, o3);
      *(uint2*)(zs + il * ZHS + i_local * ROWW + jl) = make_uint2(p01, p23);
    }
  }
  __syncthreads();

  // --- Phase 2: attention, 3 heads per wave, lane il = i-row ---
  const int irow = i0 + il;
  for (int hh = 0; hh < 3; ++hh) {
    const int h = w * 3 + hh;
    bf16x8 qf0 = *(const bf16x8*)(qb + (size_t)irow * CS + h * HD + qg * 8);
    bf16x8 qf1 = *(const bf16x8*)(qb + (size_t)irow * CS + h * HD + 32 + qg * 8);
    const __half* zh = zs + h * ZHS + il * ROWW;
    f32x4 oacc[4] = {};
    float plocal = 0.f;
    f32x4 sacc[4] = {};
    #pragma unroll
    for (int jb = 0; jb < 4; ++jb) {
      const unsigned short* kbase = kb + (size_t)(j0 + jb * 16 + il) * CS + h * HD;
      bf16x8 kf0 = *(const bf16x8*)(kbase + qg * 8);
      bf16x8 kf1 = *(const bf16x8*)(kbase + 32 + qg * 8);
      sacc[jb] = __builtin_amdgcn_mfma_f32_16x16x32_bf16(kf0, qf0, sacc[jb], 0, 0, 0);
      sacc[jb] = __builtin_amdgcn_mfma_f32_16x16x32_bf16(kf1, qf1, sacc[jb], 0, 0, 0);
    }
    unsigned int c0[4], c1[4];
    #pragma unroll
    for (int jb = 0; jb < 4; ++jb) {
      uint2 zr = *(const uint2*)(zh + jb * 16 + qg * 4);
      const __half2* hz = (const __half2*)&zr;
      float z0 = __low2float(hz[0]), z1 = __high2float(hz[0]);
      float z2 = __low2float(hz[1]), z3 = __high2float(hz[1]);
      float p0 = exp2f(fmaf(sacc[jb][0], QKS, z0));
      float p1 = exp2f(fmaf(sacc[jb][1], QKS, z1));
      float p2 = exp2f(fmaf(sacc[jb][2], QKS, z2));
      float p3 = exp2f(fmaf(sacc[jb][3], QKS, z3));
      plocal += (p0 + p1) + (p2 + p3);
      c0[jb] = cvtpk_bf16(p0, p1);
      c1[jb] = cvtpk_bf16(p2, p3);
    }
    #pragma unroll
    for (int js = 0; js < 2; ++js) {
      union { unsigned int u[4]; bf16x8 v; } pb;
      pb.u[0] = c0[2*js];
      pb.u[1] = c1[2*js];
      pb.u[2] = c0[2*js + 1];
      pb.u[3] = c1[2*js + 1];
      #pragma unroll
      for (int db = 0; db < 4; ++db) {
        bf16x8 vf = *(const bf16x8*)(vtb + (size_t)(h * HD + db * 16 + il) * NTOK + j0 + js * 32 + qg * 8);
        oacc[db] = __builtin_amdgcn_mfma_f32_16x16x32_bf16(vf, pb.v, oacc[db], 0, 0, 0);
      }
    }
    plocal += __shfl_xor(plocal, 16);
    plocal += __shfl_xor(plocal, 32);
    float* obase = Opart + ((size_t)(jc * NH + h) << 16) + ((size_t)irow << 6);
    #pragma unroll
    for (int db = 0; db < 4; ++db)
      *(float4*)(obase + db * 16 + qg * 4) = *(float4*)&oacc[db];
    if (qg == 0)
      lsum[((jc * NH + h) << 10) + irow] = plocal;
  }
}

// ---------------- combine partials (plain sums) + gating -> gob (bf16) ----------------
__global__ __launch_bounds__(256) void combine_kernel(const float* __restrict__ Opart,
    const float* __restrict__ lsum, const unsigned short* __restrict__ gbuf,
    unsigned short* __restrict__ gob) {
  int t = threadIdx.x;
  int r = blockIdx.x * 4 + (t >> 6);       // (h,i) row index
  int h = r >> 10, i = r & (NTOK - 1), d = t & 63;
  float ltot = 0.f;
  #pragma unroll
  for (int c = 0; c < JC; ++c) ltot += lsum[((c * NH + h) << 10) + i];
  float o = 0.f;
  #pragma unroll
  for (int c = 0; c < JC; ++c)
    o += Opart[((size_t)(c * NH + h) << 16) + ((size_t)i << 6) + d];
  float inv = 1.f / ltot;
  size_t off = (size_t)i * CS + h * HD + d;
  gob[off] = f2bf(o * inv * bf2f(gbuf[off]));
}

// ---------------- final GEMM: out = gob @ Wo  (f32 out) ----------------
__global__ __launch_bounds__(256) void out_gemm(const unsigned short* __restrict__ A,
    const unsigned short* __restrict__ Bt, float* __restrict__ C) {
  __shared__ __align__(16) unsigned short As[64][40];
  __shared__ __align__(16) unsigned short Bs[64][40];
  int tid = threadIdx.x;
  int wid = tid >> 6, lane = tid & 63;
  int lrow = lane & 15, lk8 = (lane >> 4) * 8;
  int row0 = blockIdx.y * 64, col0 = blockIdx.x * 64;
  int ar = tid >> 2, ak = (tid & 3) * 8;
  f32x4 acc[4] = {};
  for (int k0 = 0; k0 < CS; k0 += 32) {
    *(ushort8_t*)&As[ar][ak] = *(const ushort8_t*)(A  + (size_t)(row0 + ar) * CS + k0 + ak);
    *(ushort8_t*)&Bs[ar][ak] = *(const ushort8_t*)(Bt + (size_t)(col0 + ar) * CS + k0 + ak);
    __syncthreads();
    bf16x8 af = *(bf16x8*)&As[wid * 16 + lrow][lk8];
    #pragma unroll
    for (int nb = 0; nb < 4; ++nb) {
      bf16x8 bfr = *(bf16x8*)&Bs[nb * 16 + lrow][lk8];
      acc[nb] = __builtin_amdgcn_mfma_f32_16x16x32_bf16(af, bfr, acc[nb], 0, 0, 0);
    }
    __syncthreads();
  }
  #pragma unroll
  for (int nb = 0; nb < 4; ++nb) {
    int gcol = col0 + nb * 16 + lrow;
    #pragma unroll
    for (int r = 0; r < 4; ++r) {
      int grow = row0 + wid * 16 + (lane >> 4) * 4 + r;
      C[(size_t)grow * CS + gcol] = acc[nb][r];
    }
  }
}

extern "C" void kernel_launch(void* const* d_in, const int* in_sizes, int n_in,
                              void* d_out, int out_size, void* d_ws, size_t ws_size,
                              hipStream_t stream) {
  const float* s    = (const float*)d_in[0];
  const float* z    = (const float*)d_in[1];
  const float* mask = (const float*)d_in[2];
  const float* nss  = (const float*)d_in[3];
  const float* nsb  = (const float*)d_in[4];
  const float* Wq   = (const float*)d_in[5];
  const float* bq   = (const float*)d_in[6];
  const float* Wk   = (const float*)d_in[7];
  const float* Wv   = (const float*)d_in[8];
  const float* Wg   = (const float*)d_in[9];
  const float* nzs  = (const float*)d_in[10];
  const float* nzb  = (const float*)d_in[11];
  const float* Wz   = (const float*)d_in[12];
  const float* Wo   = (const float*)d_in[13];
  float* out = (float*)d_out;

  const size_t SN = (size_t)NTOK * CS;        // 786432
  const size_t WSZ = (size_t)CS * CS;         // 589824

  float* Opart = (float*)d_ws;                         // JC*12*1024*64 f32 = 50.3 MB
  float* lsum  = Opart + (size_t)JC * NH * NTOK * HD;  // JC*12*1024 f32
  unsigned short* sn  = (unsigned short*)(lsum + (size_t)JC * NH * NTOK);
  unsigned short* qb  = sn  + SN;
  unsigned short* kb  = qb  + SN;
  unsigned short* vtb = kb  + SN;                      // [768][1024] transposed+permuted V
  unsigned short* gbuf= vtb + SN;
  unsigned short* gob = gbuf+ SN;
  unsigned short* wt  = gob + SN;                      // 5 x [768][768]

  prep_kernel<<<NTOK + 720, 256, 0, stream>>>(s, nss, nsb, sn, Wq, Wk, Wv, Wg, Wo, wt);
  qkvg_gemm<<<dim3(48, 16), 256, 0, stream>>>(sn, wt, bq, qb, kb, vtb, gbuf);
  zbflash_kernel<<<dim3(64, JC), 256, 0, stream>>>(z, nzs, nzb, Wz, mask,
                                                   qb, kb, vtb, Opart, lsum);
  combine_kernel<<<NH * NTOK / 4, 256, 0, stream>>>(Opart, lsum, gbuf, gob);
  out_gemm<<<dim3(12, 16), 256, 0, stream>>>(gob, wt + 4 * WSZ, out);
}

// Round 14
// 175.895 us; speedup vs baseline: 1.0199x; 1.0199x over previous
//
#include <hip/hip_runtime.h>
#include <hip/hip_bf16.h>
#include <hip/hip_fp16.h>

#define CS 768
#define NTOK 1024
#define CZ 128
#define NH 12
#define HD 64
#define JC 8              // j-chunks of 128
#define ZHS 2184          // f16 units per head plane in LDS (16*136 + 8 pad)

typedef __attribute__((ext_vector_type(8))) short bf16x8;
typedef __attribute__((ext_vector_type(4))) float f32x4;
typedef __attribute__((ext_vector_type(8))) unsigned short ushort8_t;
typedef __attribute__((ext_vector_type(4))) unsigned short ushort4_t;

__device__ inline unsigned short f2bf(float f) {
  __hip_bfloat16 h = __float2bfloat16(f);
  return *reinterpret_cast<unsigned short*>(&h);
}
__device__ inline float bf2f(unsigned short u) {
  union { unsigned int i; float f; } c; c.i = ((unsigned int)u) << 16;
  return c.f;
}
__device__ inline unsigned int cvtpk_bf16(float lo, float hi) {
  unsigned int r;
  asm("v_cvt_pk_bf16_f32 %0, %1, %2" : "=v"(r) : "v"(lo), "v"(hi));
  return r;
}
__device__ inline unsigned int cvtpk_f16(float lo, float hi) {
  unsigned int r;
  asm("v_cvt_pkrtz_f16_f32 %0, %1, %2" : "=v"(r) : "v"(lo), "v"(hi));
  return r;
}

// ---------------- prep: LN(s)->bf16  +  transpose/convert 5 weights ----------------
__global__ __launch_bounds__(256) void prep_kernel(const float* __restrict__ s,
    const float* __restrict__ sc, const float* __restrict__ bi, unsigned short* __restrict__ sn,
    const float* __restrict__ W0, const float* __restrict__ W1, const float* __restrict__ W2,
    const float* __restrict__ W3, const float* __restrict__ W4, unsigned short* __restrict__ wt) {
  __shared__ float tile[64][65];
  int tid = threadIdx.x;
  if (blockIdx.x < NTOK) {
    int row = blockIdx.x;
    const float* x = s + (size_t)row * CS;
    float v0 = x[tid], v1 = x[tid + 256], v2 = x[tid + 512];
    float sum = v0 + v1 + v2;
    float sq  = v0*v0 + v1*v1 + v2*v2;
    for (int off = 1; off < 64; off <<= 1) {
      sum += __shfl_xor(sum, off);
      sq  += __shfl_xor(sq,  off);
    }
    __shared__ float ws1[4], ws2[4];
    if ((tid & 63) == 0) { ws1[tid >> 6] = sum; ws2[tid >> 6] = sq; }
    __syncthreads();
    float S = ws1[0] + ws1[1] + ws1[2] + ws1[3];
    float Q = ws2[0] + ws2[1] + ws2[2] + ws2[3];
    float mu  = S * (1.f / CS);
    float var = Q * (1.f / CS) - mu * mu;
    float rs  = rsqrtf(var + 1e-5f);
    unsigned short* y = sn + (size_t)row * CS;
    y[tid]       = f2bf((v0 - mu) * rs * sc[tid]       + bi[tid]);
    y[tid + 256] = f2bf((v1 - mu) * rs * sc[tid + 256] + bi[tid + 256]);
    y[tid + 512] = f2bf((v2 - mu) * rs * sc[tid + 512] + bi[tid + 512]);
  } else {
    int bz = blockIdx.x - NTOK;           // [0, 720)
    int w = bz / 144, rem = bz % 144;
    int kt = rem % 12, nt = rem / 12;
    const float* W = w == 0 ? W0 : w == 1 ? W1 : w == 2 ? W2 : w == 3 ? W3 : W4;
    unsigned short* Wt = wt + (size_t)w * CS * CS;
    int k0 = kt * 64, n0 = nt * 64;
    #pragma unroll
    for (int it = 0; it < 4; ++it) {
      int r = (tid >> 4) + it * 16;
      int c = (tid & 15) * 4;
      float4 vv = *(const float4*)(W + (size_t)(k0 + r) * CS + n0 + c);
      tile[r][c] = vv.x; tile[r][c+1] = vv.y; tile[r][c+2] = vv.z; tile[r][c+3] = vv.w;
    }
    __syncthreads();
    #pragma unroll
    for (int it = 0; it < 2; ++it) {
      int idx = tid + it * 256;
      int n = idx >> 3, k8 = (idx & 7) * 8;
      ushort8_t o;
      #pragma unroll
      for (int e = 0; e < 8; ++e) o[e] = f2bf(tile[k8 + e][n]);
      *(ushort8_t*)(Wt + (size_t)(n0 + n) * CS + k0 + k8) = o;
    }
  }
}

// ---------------- qkvg GEMM (standalone): [1024x768] @ [768x3072 sections] ----------------
__global__ __launch_bounds__(256) void qkvg_gemm(const unsigned short* __restrict__ A,
    const unsigned short* __restrict__ Wt, const float* __restrict__ bq,
    unsigned short* __restrict__ qb, unsigned short* __restrict__ kb,
    unsigned short* __restrict__ vtb, unsigned short* __restrict__ gbuf) {
  __shared__ __align__(16) unsigned short As[64][40];
  __shared__ __align__(16) unsigned short Bs[64][40];
  int tid = threadIdx.x;
  int wid = tid >> 6, lane = tid & 63;
  int lrow = lane & 15, lk8 = (lane >> 4) * 8;
  int row0 = blockIdx.y * 64, col0 = blockIdx.x * 64;   // col0 in [0,3072)
  int ar = tid >> 2, ak = (tid & 3) * 8;
  f32x4 acc[4] = {};
  for (int k0 = 0; k0 < CS; k0 += 32) {
    *(ushort8_t*)&As[ar][ak] = *(const ushort8_t*)(A  + (size_t)(row0 + ar) * CS + k0 + ak);
    *(ushort8_t*)&Bs[ar][ak] = *(const ushort8_t*)(Wt + (size_t)(col0 + ar) * CS + k0 + ak);
    __syncthreads();
    bf16x8 af = *(bf16x8*)&As[wid * 16 + lrow][lk8];
    #pragma unroll
    for (int nb = 0; nb < 4; ++nb) {
      bf16x8 bfr = *(bf16x8*)&Bs[nb * 16 + lrow][lk8];
      acc[nb] = __builtin_amdgcn_mfma_f32_16x16x32_bf16(af, bfr, acc[nb], 0, 0, 0);
    }
    __syncthreads();
  }
  int sect = col0 / CS;          // 0=q 1=k 2=v 3=g
  int ncol0 = col0 - sect * CS;
  int grow0 = row0 + wid * 16 + (lane >> 4) * 4;
  if (sect == 2) {
    // V transposed + column-permuted to PV's B-fragment k-slot order
    int jperm0 = ((grow0 >> 5) << 5) + 8 * (lane >> 4) + 4 * (wid & 1);
    #pragma unroll
    for (int nb = 0; nb < 4; ++nb) {
      int dg = ncol0 + nb * 16 + lrow;
      ushort4_t o;
      #pragma unroll
      for (int r = 0; r < 4; ++r) o[r] = f2bf(acc[nb][r]);
      *(ushort4_t*)(vtb + (size_t)dg * NTOK + jperm0) = o;
    }
  } else {
    unsigned short* dst = sect == 0 ? qb : sect == 1 ? kb : gbuf;
    #pragma unroll
    for (int nb = 0; nb < 4; ++nb) {
      int gcol = ncol0 + nb * 16 + lrow;
      float bv = (sect == 0) ? bq[gcol] : 0.f;
      #pragma unroll
      for (int r = 0; r < 4; ++r) {
        float val = acc[nb][r] + bv;
        if (sect == 3) val = 1.f / (1.f + __expf(-val));
        dst[(size_t)(grow0 + r) * CS + gcol] = f2bf(val);
      }
    }
  }
}

// ---------------- fused zb + flash: block = (16 i-rows, 128 j-cols, all 12 heads) ----------------
__global__ __launch_bounds__(256) void zbflash_kernel(const float* __restrict__ z,
    const float* __restrict__ gs, const float* __restrict__ gb,
    const float* __restrict__ Wz, const float* __restrict__ mask,
    const unsigned short* __restrict__ qb, const unsigned short* __restrict__ kb,
    const unsigned short* __restrict__ vtb,
    float* __restrict__ Opart, float* __restrict__ lsum) {
  __shared__ __half zs[NH * ZHS];            // 12 * 2184 * 2B = 52.4 KB
  const int i0 = blockIdx.x * 16;
  const int jc = blockIdx.y;
  const int j0 = jc * 128;
  const int tid = threadIdx.x;
  const int w = tid >> 6, lane = tid & 63;
  const int il = lane & 15, qg = lane >> 4;
  const float QKS = 0.125f * 1.44269504f;

  // --- W' = sc*Wz split-bf16 fragments + bias-dot ---
  bf16x8 whi[4], wlo[4];
  float bh = 0.f;
  #pragma unroll
  for (int m = 0; m < 4; ++m) {
    union { unsigned short u[8]; bf16x8 v; } hi, lo;
    #pragma unroll
    for (int e = 0; e < 8; ++e) {
      int c = 32 * m + 8 * qg + e;
      float wv = (il < NH) ? Wz[c * NH + il] : 0.f;
      bh = fmaf(gb[c], wv, bh);
      float wp = gs[c] * wv;
      unsigned short h = f2bf(wp);
      hi.u[e] = h;
      lo.u[e] = f2bf(wp - bf2f(h));
    }
    whi[m] = hi.v; wlo[m] = lo.v;
  }
  bh += __shfl_xor(bh, 16);
  bh += __shfl_xor(bh, 32);

  // --- Phase 1: zb tile. 128 groups of 16 pairs; wave w does groups w*32..w*32+31 ---
  for (int it = 0; it < 32; ++it) {
    int group = w * 32 + it;
    int i_local = group >> 3;               // 0..15
    int jseg = group & 7;                   // 0..7 (16-col segments)
    const float* zrow = z + ((size_t)(i0 + i_local) * NTOK + j0 + jseg * 16 + il) * CZ;
    float zv[32];
    #pragma unroll
    for (int m = 0; m < 4; ++m) {
      float4 a = *(const float4*)(zrow + 32 * m + 8 * qg);
      float4 b = *(const float4*)(zrow + 32 * m + 8 * qg + 4);
      zv[m*8+0] = a.x; zv[m*8+1] = a.y; zv[m*8+2] = a.z; zv[m*8+3] = a.w;
      zv[m*8+4] = b.x; zv[m*8+5] = b.y; zv[m*8+6] = b.z; zv[m*8+7] = b.w;
    }
    float sum = 0.f, sq = 0.f;
    #pragma unroll
    for (int e = 0; e < 32; ++e) { sum += zv[e]; sq = fmaf(zv[e], zv[e], sq); }
    sum += __shfl_xor(sum, 16); sum += __shfl_xor(sum, 32);
    sq  += __shfl_xor(sq,  16); sq  += __shfl_xor(sq,  32);
    float mu  = sum * (1.f / CZ);
    float var = sq * (1.f / CZ) - mu * mu;
    float rs  = rsqrtf(var + 1e-5f);
    float nmr = -mu * rs;
    f32x4 acc = {};
    #pragma unroll
    for (int m = 0; m < 4; ++m) {
      union { unsigned int u[4]; bf16x8 v; } hi;
      #pragma unroll
      for (int e2 = 0; e2 < 4; ++e2) {
        float n0 = fmaf(zv[m*8+e2*2],     rs, nmr);
        float n1 = fmaf(zv[m*8+e2*2 + 1], rs, nmr);
        hi.u[e2] = cvtpk_bf16(n0, n1);
      }
      acc = __builtin_amdgcn_mfma_f32_16x16x32_bf16(hi.v, whi[m], acc, 0, 0, 0);
      acc = __builtin_amdgcn_mfma_f32_16x16x32_bf16(hi.v, wlo[m], acc, 0, 0, 0);
    }
    if (il < NH) {
      int jl = jseg * 16 + 4 * qg;          // 0..127, multiple of 4
      float4 mk = *(const float4*)(mask + j0 + jl);
      float o0 = (acc[0] + bh + (1.f - mk.x) * -1000000.0f) * 1.44269504f - 16.f;
      float o1 = (acc[1] + bh + (1.f - mk.y) * -1000000.0f) * 1.44269504f - 16.f;
      float o2 = (acc[2] + bh + (1.f - mk.z) * -1000000.0f) * 1.44269504f - 16.f;
      float o3 = (acc[3] + bh + (1.f - mk.w) * -1000000.0f) * 1.44269504f - 16.f;
      unsigned int p01 = cvtpk_f16(o0, o1);
      unsigned int p23 = cvtpk_f16(o2, o3);
      *(uint2*)(zs + il * ZHS + i_local * 136 + jl) = make_uint2(p01, p23);
    }
  }
  __syncthreads();

  // --- Phase 2: attention, 3 heads per wave, lane il = i-row ---
  const int irow = i0 + il;
  for (int hh = 0; hh < 3; ++hh) {
    const int h = w * 3 + hh;
    bf16x8 qf0 = *(const bf16x8*)(qb + (size_t)irow * CS + h * HD + qg * 8);
    bf16x8 qf1 = *(const bf16x8*)(qb + (size_t)irow * CS + h * HD + 32 + qg * 8);
    const __half* zh = zs + h * ZHS + il * 136;
    f32x4 oacc[4] = {};
    float plocal = 0.f;
    #pragma unroll
    for (int jt = 0; jt < 2; ++jt) {
      int jb0 = j0 + jt * 64;
      f32x4 sacc[4] = {};
      #pragma unroll
      for (int jb = 0; jb < 4; ++jb) {
        const unsigned short* kbase = kb + (size_t)(jb0 + jb * 16 + il) * CS + h * HD;
        bf16x8 kf0 = *(const bf16x8*)(kbase + qg * 8);
        bf16x8 kf1 = *(const bf16x8*)(kbase + 32 + qg * 8);
        sacc[jb] = __builtin_amdgcn_mfma_f32_16x16x32_bf16(kf0, qf0, sacc[jb], 0, 0, 0);
        sacc[jb] = __builtin_amdgcn_mfma_f32_16x16x32_bf16(kf1, qf1, sacc[jb], 0, 0, 0);
      }
      unsigned int c0[4], c1[4];
      #pragma unroll
      for (int jb = 0; jb < 4; ++jb) {
        uint2 zr = *(const uint2*)(zh + jt * 64 + jb * 16 + qg * 4);
        const __half2* hz = (const __half2*)&zr;
        float z0 = __low2float(hz[0]), z1 = __high2float(hz[0]);
        float z2 = __low2float(hz[1]), z3 = __high2float(hz[1]);
        float p0 = exp2f(fmaf(sacc[jb][0], QKS, z0));
        float p1 = exp2f(fmaf(sacc[jb][1], QKS, z1));
        float p2 = exp2f(fmaf(sacc[jb][2], QKS, z2));
        float p3 = exp2f(fmaf(sacc[jb][3], QKS, z3));
        plocal += (p0 + p1) + (p2 + p3);
        c0[jb] = cvtpk_bf16(p0, p1);
        c1[jb] = cvtpk_bf16(p2, p3);
      }
      #pragma unroll
      for (int js = 0; js < 2; ++js) {
        union { unsigned int u[4]; bf16x8 v; } pb;
        pb.u[0] = c0[2*js];
        pb.u[1] = c1[2*js];
        pb.u[2] = c0[2*js + 1];
        pb.u[3] = c1[2*js + 1];
        #pragma unroll
        for (int db = 0; db < 4; ++db) {
          bf16x8 vf = *(const bf16x8*)(vtb + (size_t)(h * HD + db * 16 + il) * NTOK + jb0 + js * 32 + qg * 8);
          oacc[db] = __builtin_amdgcn_mfma_f32_16x16x32_bf16(vf, pb.v, oacc[db], 0, 0, 0);
        }
      }
    }
    plocal += __shfl_xor(plocal, 16);
    plocal += __shfl_xor(plocal, 32);
    float* obase = Opart + ((size_t)(jc * NH + h) << 16) + ((size_t)irow << 6);
    #pragma unroll
    for (int db = 0; db < 4; ++db)
      *(float4*)(obase + db * 16 + qg * 4) = *(float4*)&oacc[db];
    if (qg == 0)
      lsum[((jc * NH + h) << 10) + irow] = plocal;
  }
}

// ---------------- combine partials (plain sums) + gating -> gob (bf16) ----------------
__global__ __launch_bounds__(256) void combine_kernel(const float* __restrict__ Opart,
    const float* __restrict__ lsum, const unsigned short* __restrict__ gbuf,
    unsigned short* __restrict__ gob) {
  int t = threadIdx.x;
  int r = blockIdx.x * 4 + (t >> 6);       // (h,i) row index
  int h = r >> 10, i = r & (NTOK - 1), d = t & 63;
  float ltot = 0.f;
  #pragma unroll
  for (int c = 0; c < JC; ++c) ltot += lsum[((c * NH + h) << 10) + i];
  float o = 0.f;
  #pragma unroll
  for (int c = 0; c < JC; ++c)
    o += Opart[((size_t)(c * NH + h) << 16) + ((size_t)i << 6) + d];
  float inv = 1.f / ltot;
  size_t off = (size_t)i * CS + h * HD + d;
  gob[off] = f2bf(o * inv * bf2f(gbuf[off]));
}

// ---------------- final GEMM: out = gob @ Wo  (f32 out) ----------------
__global__ __launch_bounds__(256) void out_gemm(const unsigned short* __restrict__ A,
    const unsigned short* __restrict__ Bt, float* __restrict__ C) {
  __shared__ __align__(16) unsigned short As[64][40];
  __shared__ __align__(16) unsigned short Bs[64][40];
  int tid = threadIdx.x;
  int wid = tid >> 6, lane = tid & 63;
  int lrow = lane & 15, lk8 = (lane >> 4) * 8;
  int row0 = blockIdx.y * 64, col0 = blockIdx.x * 64;
  int ar = tid >> 2, ak = (tid & 3) * 8;
  f32x4 acc[4] = {};
  for (int k0 = 0; k0 < CS; k0 += 32) {
    *(ushort8_t*)&As[ar][ak] = *(const ushort8_t*)(A  + (size_t)(row0 + ar) * CS + k0 + ak);
    *(ushort8_t*)&Bs[ar][ak] = *(const ushort8_t*)(Bt + (size_t)(col0 + ar) * CS + k0 + ak);
    __syncthreads();
    bf16x8 af = *(bf16x8*)&As[wid * 16 + lrow][lk8];
    #pragma unroll
    for (int nb = 0; nb < 4; ++nb) {
      bf16x8 bfr = *(bf16x8*)&Bs[nb * 16 + lrow][lk8];
      acc[nb] = __builtin_amdgcn_mfma_f32_16x16x32_bf16(af, bfr, acc[nb], 0, 0, 0);
    }
    __syncthreads();
  }
  #pragma unroll
  for (int nb = 0; nb < 4; ++nb) {
    int gcol = col0 + nb * 16 + lrow;
    #pragma unroll
    for (int r = 0; r < 4; ++r) {
      int grow = row0 + wid * 16 + (lane >> 4) * 4 + r;
      C[(size_t)grow * CS + gcol] = acc[nb][r];
    }
  }
}

extern "C" void kernel_launch(void* const* d_in, const int* in_sizes, int n_in,
                              void* d_out, int out_size, void* d_ws, size_t ws_size,
                              hipStream_t stream) {
  const float* s    = (const float*)d_in[0];
  const float* z    = (const float*)d_in[1];
  const float* mask = (const float*)d_in[2];
  const float* nss  = (const float*)d_in[3];
  const float* nsb  = (const float*)d_in[4];
  const float* Wq   = (const float*)d_in[5];
  const float* bq   = (const float*)d_in[6];
  const float* Wk   = (const float*)d_in[7];
  const float* Wv   = (const float*)d_in[8];
  const float* Wg   = (const float*)d_in[9];
  const float* nzs  = (const float*)d_in[10];
  const float* nzb  = (const float*)d_in[11];
  const float* Wz   = (const float*)d_in[12];
  const float* Wo   = (const float*)d_in[13];
  float* out = (float*)d_out;

  const size_t SN = (size_t)NTOK * CS;        // 786432
  const size_t WSZ = (size_t)CS * CS;         // 589824

  float* Opart = (float*)d_ws;                         // JC*12*1024*64 f32 = 25 MB
  float* lsum  = Opart + (size_t)JC * NH * NTOK * HD;  // JC*12*1024 f32
  unsigned short* sn  = (unsigned short*)(lsum + (size_t)JC * NH * NTOK);
  unsigned short* qb  = sn  + SN;
  unsigned short* kb  = qb  + SN;
  unsigned short* vtb = kb  + SN;                      // [768][1024] transposed+permuted V
  unsigned short* gbuf= vtb + SN;
  unsigned short* gob = gbuf+ SN;
  unsigned short* wt  = gob + SN;                      // 5 x [768][768]

  prep_kernel<<<NTOK + 720, 256, 0, stream>>>(s, nss, nsb, sn, Wq, Wk, Wv, Wg, Wo, wt);
  qkvg_gemm<<<dim3(48, 16), 256, 0, stream>>>(sn, wt, bq, qb, kb, vtb, gbuf);
  zbflash_kernel<<<dim3(64, JC), 256, 0, stream>>>(z, nzs, nzb, Wz, mask,
                                                   qb, kb, vtb, Opart, lsum);
  combine_kernel<<<NH * NTOK / 4, 256, 0, stream>>>(Opart, lsum, gbuf, gob);
  out_gemm<<<dim3(12, 16), 256, 0, stream>>>(gob, wt + 4 * WSZ, out);
}